// Round 3
// baseline (1125.821 us; speedup 1.0000x reference)
//
#include <hip/hip_runtime.h>
#include <math.h>

// S4D forward (conv mode) via chunked linear recurrence.
// y[b,l,d] = D[d]*x[b,l,d] + sum_n CB[d,n] * h_n[l],  h_n[l] = a_n h_n[l-1] + x[l]
// a = exp(dt*A), CB = C * expm1(dt*A)/A * B, A_n = -0.5*(n+1)
//
// Round-2 post-mortem: __launch_bounds__(256,6) capped the UNIFIED reg file
// at 85/wave -> acc[32] spilled to scratch (WRITE_SIZE 565 MB, 370 us).
// On gfx950 AGPRs share the budget, so an over-tight bound means scratch,
// not AGPR. Fix: T=64 (u-region back to 67 MB, L3-resident; scan/state
// traffic halved) + n-group streaming with a budget that FITS:
//   out:   acc[64] + a/cb/h[24] + ptrs ~= 105 regs -> bounds (256,4), cap 128.
//   state: a[16]+h[16] ~= 45 regs            -> bounds (256,8), cap 64.
// x re-read per n-group from L1/L2 (537 MB at L2 BW ~16 us, overlapped).
// Scan gets an explicit next-u prefetch to overlap the dependent chain.

namespace {
constexpr int kBatch = 8;
constexpr int kLen   = 2048;
constexpr int kD     = 1024;
constexpr int kN     = 64;         // states
constexpr int kT     = 64;         // chunk length
constexpr int kC     = kLen / kT;  // 32 chunks

constexpr long kU     = (long)kBatch * kC * kN * kD;  // 16,777,216 floats
constexpr long kAOff  = kU;                           // a[n][d]
constexpr long kCbOff = kAOff + (long)kN * kD;        // cb[n][d]
constexpr long kAtOff = kCbOff + (long)kN * kD;       // a^T[n][d]
// total ws: (16777216 + 3*65536)*4 B = 67,895,296 B (~64.8 MiB)
}  // namespace

__global__ void s4d_coef_kernel(const float* __restrict__ log_dt,
                                const float* __restrict__ Bm,
                                const float* __restrict__ Cm,
                                float* __restrict__ ws) {
  int tid = blockIdx.x * blockDim.x + threadIdx.x;  // 65536 threads
  int d = tid & (kD - 1);
  int n = tid >> 10;
  float dt  = expf(log_dt[d]);
  float An  = -0.5f * (float)(n + 1);
  float dtA = dt * An;
  float a   = expf(dtA);
  float bbar = (expm1f(dtA) / An) * Bm[d * kN + n];
  float cb   = Cm[d * kN + n] * bbar;
  float aT   = expf(dtA * (float)kT);  // a^64
  ws[kAOff  + (long)n * kD + d] = a;
  ws[kCbOff + (long)n * kD + d] = cb;
  ws[kAtOff + (long)n * kD + d] = aT;
}

// Phase 1: chunk-local end states (zero initial state). n-groups of 16 in
// registers; x[t] re-read per group (4x) from L1/L2.
__global__ __launch_bounds__(256, 8) void s4d_state_kernel(
    const float* __restrict__ x, float* __restrict__ ws) {
  constexpr int NG = 16;
  int tid = blockIdx.x * blockDim.x + threadIdx.x;  // 262144 threads
  int d  = tid & (kD - 1);   // consecutive lanes -> consecutive d: coalesced
  int bc = tid >> 10;
  int b  = bc >> 5;
  int c  = bc & (kC - 1);

  const float* xp = x + ((long)b * kLen + (long)c * kT) * kD + d;
  const float* ap = ws + kAOff + d;
  float* up = ws + ((long)bc * kN) * kD + d;

#pragma unroll 1
  for (int g = 0; g < kN; g += NG) {
    float a[NG], h[NG];
#pragma unroll
    for (int i = 0; i < NG; ++i) {
      a[i] = ap[(long)(g + i) * kD];
      h[i] = 0.f;
    }
#pragma unroll
    for (int t = 0; t < kT; ++t) {
      float xt = xp[(long)t * kD];
#pragma unroll
      for (int i = 0; i < NG; ++i) h[i] = fmaf(h[i], a[i], xt);
    }
#pragma unroll
    for (int i = 0; i < NG; ++i) up[(long)(g + i) * kD] = h[i];
  }
}

// Phase 2: inter-chunk scan with software prefetch of the next u.
// After this, ws[u-region] holds s_start[c] = initial state for chunk c.
__global__ __launch_bounds__(256) void s4d_scan_kernel(float* __restrict__ ws) {
  int tid = blockIdx.x * blockDim.x + threadIdx.x;  // 524288 threads
  int d  = tid & (kD - 1);
  int bn = tid >> 10;
  int n  = bn & (kN - 1);
  int b  = bn >> 6;
  float aT = ws[kAtOff + (long)n * kD + d];
  float* up = ws + ((long)b * kC * kN + n) * kD + d;
  const long cstride = (long)kN * kD;
  float s = 0.f;
  float u = up[0];
#pragma unroll 1
  for (int c = 0; c < kC; ++c) {
    float unext = (c + 1 < kC) ? up[(long)(c + 1) * cstride] : 0.f;
    up[(long)c * cstride] = s;  // in place: u[c] -> s_start[c]
    s = fmaf(aT, s, u);
    u = unext;
  }
}

// Phase 3: full output. acc[T=64] register-resident (fits the 128-reg cap);
// n-groups of 8 streamed; x[t] re-read per group from L1/L2. Accumulation
// order identical to prior rounds (n ascending into acc[t]).
__global__ __launch_bounds__(256, 4) void s4d_out_kernel(
    const float* __restrict__ x, const float* __restrict__ Dv,
    float* __restrict__ y, const float* __restrict__ ws) {
  constexpr int NG = 8;
  int tid = blockIdx.x * blockDim.x + threadIdx.x;  // 262144 threads
  int d  = tid & (kD - 1);
  int bc = tid >> 10;
  int b  = bc >> 5;
  int c  = bc & (kC - 1);

  const float* xp = x + ((long)b * kLen + (long)c * kT) * kD + d;
  float Dd = Dv[d];

  float acc[kT];
#pragma unroll
  for (int t = 0; t < kT; ++t) acc[t] = Dd * xp[(long)t * kD];

  const float* ap  = ws + kAOff + d;
  const float* cbp = ws + kCbOff + d;
  const float* sp  = ws + ((long)bc * kN) * kD + d;

#pragma unroll 1
  for (int g = 0; g < kN; g += NG) {
    float a[NG], cb[NG], h[NG];
#pragma unroll
    for (int i = 0; i < NG; ++i) {
      long o = (long)(g + i) * kD;
      a[i]  = ap[o];
      cb[i] = cbp[o];
      h[i]  = sp[o];
    }
#pragma unroll
    for (int t = 0; t < kT; ++t) {
      float xt = xp[(long)t * kD];
#pragma unroll
      for (int i = 0; i < NG; ++i) {
        h[i]   = fmaf(h[i], a[i], xt);
        acc[t] = fmaf(cb[i], h[i], acc[t]);
      }
    }
  }

  float* yp = y + ((long)b * kLen + (long)c * kT) * kD + d;
#pragma unroll
  for (int t = 0; t < kT; ++t) yp[(long)t * kD] = acc[t];
}

extern "C" void kernel_launch(void* const* d_in, const int* in_sizes, int n_in,
                              void* d_out, int out_size, void* d_ws,
                              size_t ws_size, hipStream_t stream) {
  const float* x      = (const float*)d_in[0];
  const float* log_dt = (const float*)d_in[1];
  const float* Bm     = (const float*)d_in[2];
  const float* Cm     = (const float*)d_in[3];
  const float* Dv     = (const float*)d_in[4];
  float* y  = (float*)d_out;
  float* ws = (float*)d_ws;

  hipLaunchKernelGGL(s4d_coef_kernel, dim3((kN * kD) / 256), dim3(256), 0,
                     stream, log_dt, Bm, Cm, ws);
  hipLaunchKernelGGL(s4d_state_kernel, dim3((kBatch * kC * kD) / 256),
                     dim3(256), 0, stream, x, ws);
  hipLaunchKernelGGL(s4d_scan_kernel, dim3((kBatch * kN * kD) / 256),
                     dim3(256), 0, stream, ws);
  hipLaunchKernelGGL(s4d_out_kernel, dim3((kBatch * kC * kD) / 256),
                     dim3(256), 0, stream, x, Dv, y, ws);
}

// Round 4
// 806.294 us; speedup vs baseline: 1.3963x; 1.3963x over previous
//
#include <hip/hip_runtime.h>
#include <math.h>

// S4D forward (conv mode) via chunked linear recurrence.
// y[b,l,d] = D[d]*x[b,l,d] + sum_n CB[d,n] * h_n[l],  h_n[l] = a_n h_n[l-1] + x[l]
// a = exp(dt*A), CB = C * expm1(dt*A)/A * B, A_n = -0.5*(n+1)
//
// Round-3 post-mortem: acc[64] spilled to scratch under a 128-reg cap
// (VGPR=64 reported, WRITE_SIZE 1.85 GB). Rounds that worked kept arrays in
// AGPRs (slow but not catastrophic). Fix for out kernel: give the h-state an
// explicit home in LDS (per-thread private column hs[n][tid] -> no barriers,
// no bank conflicts), tile t by 32 and n by 8 so the register working set is
// xv[32]+acc[32]+{a,cb,h}[8] ~= 110 regs, and set __launch_bounds__(256,2):
// LDS (64 KB/block) already limits residency to 2 blocks/CU, so min-waves=2
// raises the VGPR cap to 256 and removes spill pressure entirely.
// LDS traffic: 256 ds ops per 8192 FMAs (3%). Accumulation order unchanged.

namespace {
constexpr int kBatch = 8;
constexpr int kLen   = 2048;
constexpr int kD     = 1024;
constexpr int kN     = 64;         // states
constexpr int kT     = 64;         // chunk length
constexpr int kC     = kLen / kT;  // 32 chunks

constexpr long kU     = (long)kBatch * kC * kN * kD;  // 16,777,216 floats
constexpr long kAOff  = kU;                           // a[n][d]
constexpr long kCbOff = kAOff + (long)kN * kD;        // cb[n][d]
constexpr long kAtOff = kCbOff + (long)kN * kD;       // a^T[n][d]
// total ws: (16777216 + 3*65536)*4 B = 67,895,296 B (~64.8 MiB)
}  // namespace

__global__ void s4d_coef_kernel(const float* __restrict__ log_dt,
                                const float* __restrict__ Bm,
                                const float* __restrict__ Cm,
                                float* __restrict__ ws) {
  int tid = blockIdx.x * blockDim.x + threadIdx.x;  // 65536 threads
  int d = tid & (kD - 1);
  int n = tid >> 10;
  float dt  = expf(log_dt[d]);
  float An  = -0.5f * (float)(n + 1);
  float dtA = dt * An;
  float a   = expf(dtA);
  float bbar = (expm1f(dtA) / An) * Bm[d * kN + n];
  float cb   = Cm[d * kN + n] * bbar;
  float aT   = expf(dtA * (float)kT);  // a^64
  ws[kAOff  + (long)n * kD + d] = a;
  ws[kCbOff + (long)n * kD + d] = cb;
  ws[kAtOff + (long)n * kD + d] = aT;
}

// Phase 1: chunk-local end states (zero initial state). n-groups of 16 in
// registers; x[t] re-read per group (4x) from L1/L2. ~45 live regs, cap 64.
__global__ __launch_bounds__(256, 8) void s4d_state_kernel(
    const float* __restrict__ x, float* __restrict__ ws) {
  constexpr int NG = 16;
  int tid = blockIdx.x * blockDim.x + threadIdx.x;  // 262144 threads
  int d  = tid & (kD - 1);   // consecutive lanes -> consecutive d: coalesced
  int bc = tid >> 10;
  int b  = bc >> 5;
  int c  = bc & (kC - 1);

  const float* xp = x + ((long)b * kLen + (long)c * kT) * kD + d;
  const float* ap = ws + kAOff + d;
  float* up = ws + ((long)bc * kN) * kD + d;

#pragma unroll 1
  for (int g = 0; g < kN; g += NG) {
    float a[NG], h[NG];
#pragma unroll
    for (int i = 0; i < NG; ++i) {
      a[i] = ap[(long)(g + i) * kD];
      h[i] = 0.f;
    }
#pragma unroll
    for (int t = 0; t < kT; ++t) {
      float xt = xp[(long)t * kD];
#pragma unroll
      for (int i = 0; i < NG; ++i) h[i] = fmaf(h[i], a[i], xt);
    }
#pragma unroll
    for (int i = 0; i < NG; ++i) up[(long)(g + i) * kD] = h[i];
  }
}

// Phase 2: inter-chunk scan (R0's simple in-place form).
// After this, ws[u-region] holds s_start[c] = initial state for chunk c.
__global__ __launch_bounds__(256) void s4d_scan_kernel(float* __restrict__ ws) {
  int tid = blockIdx.x * blockDim.x + threadIdx.x;  // 524288 threads
  int d  = tid & (kD - 1);
  int bn = tid >> 10;
  int n  = bn & (kN - 1);
  int b  = bn >> 6;
  float aT = ws[kAtOff + (long)n * kD + d];
  float* up = ws + ((long)b * kC * kN + n) * kD + d;
  const long cstride = (long)kN * kD;
  float s = 0.f;
#pragma unroll 1
  for (int c = 0; c < kC; ++c) {
    float u = up[(long)c * cstride];
    up[(long)c * cstride] = s;  // in place: u[c] -> s_start[c]
    s = fmaf(aT, s, u);
  }
}

// Phase 3: full output. h-state lives in LDS (private column per thread,
// no barriers needed); t tiled by TT=32, n grouped by NG=8. Registers:
// xv[32]+acc[32]+a/cb/h[8 each] ~= 110 live under a 256 cap (LDS already
// limits to 2 blocks/CU, so min-waves=2 costs nothing).
__global__ __launch_bounds__(256, 2) void s4d_out_kernel(
    const float* __restrict__ x, const float* __restrict__ Dv,
    float* __restrict__ y, const float* __restrict__ ws) {
  constexpr int TT = 32;
  constexpr int NG = 8;
  __shared__ float hs[kN][256];  // 64 KB; hs[n][tid] -> conflict-free

  int tidx = threadIdx.x;
  int tid = blockIdx.x * blockDim.x + tidx;  // 262144 threads
  int d  = tid & (kD - 1);
  int bc = tid >> 10;
  int b  = bc >> 5;
  int c  = bc & (kC - 1);

  const float* xp  = x + ((long)b * kLen + (long)c * kT) * kD + d;
  const float* ap  = ws + kAOff + d;
  const float* cbp = ws + kCbOff + d;
  const float* sp  = ws + ((long)bc * kN) * kD + d;
  float* yp = y + ((long)b * kLen + (long)c * kT) * kD + d;
  float Dd = Dv[d];

  // init h state from s_start (each thread owns its own LDS column)
#pragma unroll 4
  for (int n = 0; n < kN; ++n) hs[n][tidx] = sp[(long)n * kD];

#pragma unroll 1
  for (int tt = 0; tt < kT; tt += TT) {
    float xv[TT], acc[TT];
#pragma unroll
    for (int t = 0; t < TT; ++t) {
      xv[t]  = xp[(long)(tt + t) * kD];
      acc[t] = Dd * xv[t];
    }
#pragma unroll 1
    for (int g = 0; g < kN; g += NG) {
      float a[NG], cb[NG], h[NG];
#pragma unroll
      for (int i = 0; i < NG; ++i) {
        long o = (long)(g + i) * kD;
        a[i]  = ap[o];
        cb[i] = cbp[o];
        h[i]  = hs[g + i][tidx];
      }
#pragma unroll
      for (int t = 0; t < TT; ++t) {
#pragma unroll
        for (int i = 0; i < NG; ++i) {
          h[i]   = fmaf(h[i], a[i], xv[t]);
          acc[t] = fmaf(cb[i], h[i], acc[t]);
        }
      }
      if (tt + TT < kT) {
#pragma unroll
        for (int i = 0; i < NG; ++i) hs[g + i][tidx] = h[i];
      }
    }
#pragma unroll
    for (int t = 0; t < TT; ++t) yp[(long)(tt + t) * kD] = acc[t];
  }
}

extern "C" void kernel_launch(void* const* d_in, const int* in_sizes, int n_in,
                              void* d_out, int out_size, void* d_ws,
                              size_t ws_size, hipStream_t stream) {
  const float* x      = (const float*)d_in[0];
  const float* log_dt = (const float*)d_in[1];
  const float* Bm     = (const float*)d_in[2];
  const float* Cm     = (const float*)d_in[3];
  const float* Dv     = (const float*)d_in[4];
  float* y  = (float*)d_out;
  float* ws = (float*)d_ws;

  hipLaunchKernelGGL(s4d_coef_kernel, dim3((kN * kD) / 256), dim3(256), 0,
                     stream, log_dt, Bm, Cm, ws);
  hipLaunchKernelGGL(s4d_state_kernel, dim3((kBatch * kC * kD) / 256),
                     dim3(256), 0, stream, x, ws);
  hipLaunchKernelGGL(s4d_scan_kernel, dim3((kBatch * kN * kD) / 256),
                     dim3(256), 0, stream, ws);
  hipLaunchKernelGGL(s4d_out_kernel, dim3((kBatch * kC * kD) / 256),
                     dim3(256), 0, stream, x, Dv, y, ws);
}

// Round 5
// 223.243 us; speedup vs baseline: 5.0430x; 3.6117x over previous
//
#include <hip/hip_runtime.h>
#include <math.h>

// S4D forward (conv mode) via chunked linear recurrence.
// y[b,l,d] = D[d]*x[b,l,d] + sum_n CB[d,n] * h_n[l],  h_n[l] = a_n h_n[l-1] + x[l]
// a = exp(dt*A), CB = C * expm1(dt*A)/A * B, A_n = -0.5*(n+1)
//
// Round-4 post-mortem: every two-level tiling (t-tile x n-group with arrays
// live across a rolled loop) or tight wave cap spills wholesale to scratch
// (R2/R3/R4: WRITE_SIZE 0.5-1.9 GB). The single-level skeleton (xv[T] loaded
// once, rolled n-loop, unrolled t-loop, generous bounds) AGPR-parks cleanly
// (R0: 81.6us, R1: 73.6us; zero scratch). This round keeps R0's skeleton
// EXACTLY and only widens the n-loop: 8 states share each t-sweep, so the
// per-t AGPR traffic (xv read, acc read+write) is amortized over 16 FMAs
// instead of 2. Issue slots for out: ~20480 -> ~9700. Same accumulation
// order over n (ascending) -> bitwise-identical output.

namespace {
constexpr int kBatch = 8;
constexpr int kLen   = 2048;
constexpr int kD     = 1024;
constexpr int kN     = 64;         // states
constexpr int kT     = 64;         // chunk length
constexpr int kC     = kLen / kT;  // 32 chunks

constexpr long kU     = (long)kBatch * kC * kN * kD;  // 16,777,216 floats
constexpr long kAOff  = kU;                           // a[n][d]
constexpr long kCbOff = kAOff + (long)kN * kD;        // cb[n][d]
constexpr long kAtOff = kCbOff + (long)kN * kD;       // a^T[n][d]
// total ws: (16777216 + 3*65536)*4 B = 67,895,296 B (~64.8 MiB)
}  // namespace

__global__ void s4d_coef_kernel(const float* __restrict__ log_dt,
                                const float* __restrict__ Bm,
                                const float* __restrict__ Cm,
                                float* __restrict__ ws) {
  int tid = blockIdx.x * blockDim.x + threadIdx.x;  // 65536 threads
  int d = tid & (kD - 1);
  int n = tid >> 10;
  float dt  = expf(log_dt[d]);
  float An  = -0.5f * (float)(n + 1);
  float dtA = dt * An;
  float a   = expf(dtA);
  float bbar = (expm1f(dtA) / An) * Bm[d * kN + n];
  float cb   = Cm[d * kN + n] * bbar;
  float aT   = expf(dtA * (float)kT);  // a^64
  ws[kAOff  + (long)n * kD + d] = a;
  ws[kCbOff + (long)n * kD + d] = cb;
  ws[kAtOff + (long)n * kD + d] = aT;
}

// Phase 1: chunk-local end states (zero initial state). R0 skeleton
// (xv[64] loaded once; AGPR-parked) with 8 h-chains sharing each xv read.
__global__ __launch_bounds__(256) void s4d_state_kernel(
    const float* __restrict__ x, float* __restrict__ ws) {
  constexpr int NG = 8;
  int tid = blockIdx.x * blockDim.x + threadIdx.x;  // 262144 threads
  int d  = tid & (kD - 1);   // consecutive lanes -> consecutive d: coalesced
  int bc = tid >> 10;
  int b  = bc >> 5;
  int c  = bc & (kC - 1);

  const float* xp = x + ((long)b * kLen + (long)c * kT) * kD + d;
  float xv[kT];
#pragma unroll
  for (int t = 0; t < kT; ++t) xv[t] = xp[(long)t * kD];

  const float* ap = ws + kAOff + d;
  float* up = ws + ((long)bc * kN) * kD + d;
#pragma unroll 1
  for (int g = 0; g < kN; g += NG) {
    float a[NG], h[NG];
#pragma unroll
    for (int i = 0; i < NG; ++i) {
      a[i] = ap[(long)(g + i) * kD];
      h[i] = 0.f;
    }
#pragma unroll
    for (int t = 0; t < kT; ++t) {
      float xt = xv[t];
#pragma unroll
      for (int i = 0; i < NG; ++i) h[i] = fmaf(h[i], a[i], xt);
    }
#pragma unroll
    for (int i = 0; i < NG; ++i) up[(long)(g + i) * kD] = h[i];
  }
}

// Phase 2: inter-chunk scan (R0 verbatim). After this, ws[u-region] holds
// s_start[c] = state at the END of chunk c-1 (initial state for chunk c).
__global__ void s4d_scan_kernel(float* __restrict__ ws) {
  int tid = blockIdx.x * blockDim.x + threadIdx.x;  // 524288 threads
  int d  = tid & (kD - 1);
  int bn = tid >> 10;
  int n  = bn & (kN - 1);
  int b  = bn >> 6;
  float aT = ws[kAtOff + (long)n * kD + d];
  float* up = ws + ((long)b * kC * kN + n) * kD + d;
  const long cstride = (long)kN * kD;
  float s = 0.f;
#pragma unroll 1
  for (int c = 0; c < kC; ++c) {
    float u = up[(long)c * cstride];
    up[(long)c * cstride] = s;  // in place: u[c] -> s_start[c]
    s = fmaf(aT, s, u);
  }
}

// Phase 3: full output. R0 skeleton (xv[64]+acc[64] AGPR-parked, single-level
// n-loop, bounds (256,2) -> 256-reg unified cap, proven no-scratch) with
// 8 states sharing each t-sweep: per t, 1 xv read + 1 acc read/write
// amortized over 16 FMAs.
__global__ __launch_bounds__(256, 2) void s4d_out_kernel(
    const float* __restrict__ x, const float* __restrict__ Dv,
    float* __restrict__ y, const float* __restrict__ ws) {
  constexpr int NG = 8;
  int tid = blockIdx.x * blockDim.x + threadIdx.x;  // 262144 threads
  int d  = tid & (kD - 1);
  int bc = tid >> 10;
  int b  = bc >> 5;
  int c  = bc & (kC - 1);

  const float* xp = x + ((long)b * kLen + (long)c * kT) * kD + d;
  float xv[kT];
#pragma unroll
  for (int t = 0; t < kT; ++t) xv[t] = xp[(long)t * kD];

  float Dd = Dv[d];
  float acc[kT];
#pragma unroll
  for (int t = 0; t < kT; ++t) acc[t] = Dd * xv[t];

  const float* ap  = ws + kAOff + d;
  const float* cbp = ws + kCbOff + d;
  const float* sp  = ws + ((long)bc * kN) * kD + d;

#pragma unroll 1
  for (int g = 0; g < kN; g += NG) {
    float a[NG], cb[NG], h[NG];
#pragma unroll
    for (int i = 0; i < NG; ++i) {
      long o = (long)(g + i) * kD;
      a[i]  = ap[o];
      cb[i] = cbp[o];
      h[i]  = sp[o];  // initial state for this chunk
    }
#pragma unroll
    for (int t = 0; t < kT; ++t) {
      float xt = xv[t];
      float s  = acc[t];
#pragma unroll
      for (int i = 0; i < NG; ++i) {
        h[i] = fmaf(h[i], a[i], xt);
        s    = fmaf(cb[i], h[i], s);
      }
      acc[t] = s;
    }
  }

  float* yp = y + ((long)b * kLen + (long)c * kT) * kD + d;
#pragma unroll
  for (int t = 0; t < kT; ++t) yp[(long)t * kD] = acc[t];
}

extern "C" void kernel_launch(void* const* d_in, const int* in_sizes, int n_in,
                              void* d_out, int out_size, void* d_ws,
                              size_t ws_size, hipStream_t stream) {
  const float* x      = (const float*)d_in[0];
  const float* log_dt = (const float*)d_in[1];
  const float* Bm     = (const float*)d_in[2];
  const float* Cm     = (const float*)d_in[3];
  const float* Dv     = (const float*)d_in[4];
  float* y  = (float*)d_out;
  float* ws = (float*)d_ws;

  hipLaunchKernelGGL(s4d_coef_kernel, dim3((kN * kD) / 256), dim3(256), 0,
                     stream, log_dt, Bm, Cm, ws);
  hipLaunchKernelGGL(s4d_state_kernel, dim3((kBatch * kC * kD) / 256),
                     dim3(256), 0, stream, x, ws);
  hipLaunchKernelGGL(s4d_scan_kernel, dim3((kBatch * kN * kD) / 256),
                     dim3(256), 0, stream, ws);
  hipLaunchKernelGGL(s4d_out_kernel, dim3((kBatch * kC * kD) / 256),
                     dim3(256), 0, stream, x, Dv, y, ws);
}